// Round 9
// baseline (43.368 us; speedup 1.0000x reference)
//
#include <hip/hip_runtime.h>
#include <hip/hip_bf16.h>

// Problem: B=16, C=256, H=64, W=64, OUT=256
//   scale[b,c] = mean(context[b,c,:,:])
//   out[b,o,hw] = sum_c w1[o,c]*scale[b,c]*x[b,c,hw] + b1[o]
// R9: R8 with the kt=3 buffer-index bug fixed (compute read bst[3] -- OOB;
//     tile 3 lives in buf0 per stage(3,0)). Pipeline structure unchanged:
//   - A-prefetch issued BEFORE staging each kt (vmcnt FIFO: waiting on A no
//     longer force-drains the staging loads)
//   - triple-buffered LDS + counted s_waitcnt vmcnt + raw s_barrier (T4):
//     staging flies 2 kt deep, no vmcnt(0) drain in the loop.

typedef __attribute__((ext_vector_type(8))) short short8;
typedef __attribute__((ext_vector_type(16))) float f32x16;
typedef __attribute__((ext_vector_type(4))) unsigned int u32x4;

static __device__ __forceinline__ unsigned int bfbits(float f) {
    unsigned int u = __float_as_uint(f);
    return u + 0x7FFFu + ((u >> 16) & 1u);  // bf16 (RTNE) in bits 16..31
}

static __device__ __forceinline__ unsigned int pkbf(float lo, float hi) {
#if __has_builtin(__builtin_amdgcn_perm)
    return __builtin_amdgcn_perm(bfbits(hi), bfbits(lo), 0x07060302u);
#else
    return (bfbits(lo) >> 16) | (bfbits(hi) & 0xffff0000u);
#endif
}

// async global->LDS, 16B per lane (linear LDS dest: wave base + lane*16)
static __device__ __forceinline__ void gload16(const void* g, void* l) {
    __builtin_amdgcn_global_load_lds(
        (const __attribute__((address_space(1))) unsigned int*)g,
        (__attribute__((address_space(3))) unsigned int*)l, 16, 0, 0);
}

// ---------------- Kernel 1: scale[b*256+c] = mean over 4096 elems ----------
__global__ __launch_bounds__(256) void scale_kernel(const float* __restrict__ ctx,
                                                    float* __restrict__ scale) {
    const int bc = blockIdx.x;              // 0..4095
    const float4* p = (const float4*)(ctx + (size_t)bc * 4096);
    const int t = threadIdx.x;
    float s = 0.f;
#pragma unroll
    for (int k = 0; k < 4; k++) {
        float4 v = p[t + k * 256];
        s += v.x + v.y + v.z + v.w;
    }
#pragma unroll
    for (int off = 32; off > 0; off >>= 1) s += __shfl_down(s, off);
    __shared__ float ws[4];
    if ((t & 63) == 0) ws[t >> 6] = s;
    __syncthreads();
    if (t == 0) scale[bc] = (ws[0] + ws[1] + ws[2] + ws[3]) * (1.0f / 4096.0f);
}

// ---------------- Kernel 2: w2f = scale-folded w1, 32x32x16-fragment layout -
// w2f (ushort): [((b*16+ks)*8 + mt)*64 + lane]*8 + e
//   = bf16( w1[mt*32+(lane&31)][ks*16+(lane>>5)*8+e] * scale[b][same c] )
__global__ __launch_bounds__(256) void w2f_kernel(const float* __restrict__ w1,
                                                  const float* __restrict__ scale,
                                                  unsigned short* __restrict__ w2f) {
    const int gt = blockIdx.x * 256 + threadIdx.x;  // 0..131071
    const int l = gt & 63;
    const int mt = (gt >> 6) & 7;
    const int ks = (gt >> 9) & 15;
    const int b = gt >> 13;
    const int row = mt * 32 + (l & 31);
    const int c0 = ks * 16 + (l >> 5) * 8;

    const float* wr = w1 + row * 256 + c0;
    const float* sc = scale + b * 256 + c0;
    float4 wv0 = *(const float4*)(wr);
    float4 wv1 = *(const float4*)(wr + 4);
    float4 sv0 = *(const float4*)(sc);
    float4 sv1 = *(const float4*)(sc + 4);

    u32x4 pv;
    pv[0] = pkbf(wv0.x * sv0.x, wv0.y * sv0.y);
    pv[1] = pkbf(wv0.z * sv0.z, wv0.w * sv0.w);
    pv[2] = pkbf(wv1.x * sv1.x, wv1.y * sv1.y);
    pv[3] = pkbf(wv1.z * sv1.z, wv1.w * sv1.w);
    *(u32x4*)(w2f + (size_t)gt * 8) = pv;   // coalesced 16B store
}

// ---------------- Kernel 3: per-batch GEMM out = A(w2f) * bf16(x) + b1 ------
// 1024 blocks: b = bid>>6, col tile (bid&63)*64. 4 waves; wave w = rows [64w,+64)
// as 2x2 MFMA-32x32 tiles over 64 cols. B staged f32 [64k][64c], 3-buffered.
__global__ __launch_bounds__(256, 3) void gemm_kernel(const float* __restrict__ x,
                                                      const unsigned short* __restrict__ w2f,
                                                      const float* __restrict__ b1,
                                                      float* __restrict__ out) {
    __shared__ float bst[3][4096];     // 3 x (64k x 64c f32) = 48 KiB

    const int bid = blockIdx.x;        // 1024
    const int b = bid >> 6;
    const int hw0 = (bid & 63) * 64;
    const int tid = threadIdx.x;
    const int w = tid >> 6;
    const int lane = tid & 63;
    const int l31 = lane & 31;
    const int lh = lane >> 5;          // 0/1
    const int o0 = w * 64;

    const unsigned short* Af = w2f + (size_t)b * 65536;   // [16ks][8mt][64l][8]
    const float* Xb = x + (size_t)b * (256 * 4096) + hw0;

    f32x16 acc[2][2];
#pragma unroll
    for (int mtl = 0; mtl < 2; mtl++)
#pragma unroll
        for (int ntl = 0; ntl < 2; ntl++) acc[mtl][ntl] = (f32x16)(0.f);

    const int bbase = lh * 512 + l31;  // dword idx; + ntl*32 + sub*1024 + e*64

    auto stage = [&](int kt, int buf) {
#pragma unroll
        for (int i = 0; i < 4; i++) {
            const int idx = i * 256 + tid;          // granule 0..1023
            gload16(Xb + (size_t)(kt * 64 + (idx >> 4)) * 4096 + (idx & 15) * 4,
                    &bst[buf][idx * 4]);
        }
    };
    auto afetch = [&](int kt, short8 a[4][2]) {
#pragma unroll
        for (int sub = 0; sub < 4; sub++)
#pragma unroll
            for (int mtl = 0; mtl < 2; mtl++)
                a[sub][mtl] = *(const short8*)(
                    Af + (((size_t)(kt * 4 + sub) * 8 + (w * 2 + mtl)) * 64 + lane) * 8);
    };
    auto compute = [&](int buf, short8 a[4][2]) {
        const float* bb = bst[buf];
#pragma unroll
        for (int sub = 0; sub < 4; sub++) {
#pragma unroll
            for (int ntl = 0; ntl < 2; ntl++) {
                float bf32[8];
#pragma unroll
                for (int e = 0; e < 8; e++)
                    bf32[e] = bb[bbase + ntl * 32 + sub * 1024 + e * 64];
                u32x4 pv;
#pragma unroll
                for (int j = 0; j < 4; j++) pv[j] = pkbf(bf32[2 * j], bf32[2 * j + 1]);
                short8 bfr = __builtin_bit_cast(short8, pv);
#pragma unroll
                for (int mtl = 0; mtl < 2; mtl++)
                    acc[mtl][ntl] = __builtin_amdgcn_mfma_f32_32x32x16_bf16(
                        a[sub][mtl], bfr, acc[mtl][ntl], 0, 0, 0);
            }
        }
    };

    short8 a[4][2];

    // prologue: 2 tiles in flight
    stage(0, 0);
    stage(1, 1);

    // kt=0: outstanding t0(4)+t1(4)+A0(8)=16 -> vmcnt(12) retires t0
    afetch(0, a);
    asm volatile("s_waitcnt vmcnt(12)" ::: "memory");
    __builtin_amdgcn_s_barrier();
    __builtin_amdgcn_sched_barrier(0);
    stage(2, 2);
    compute(0, a);

    // kt=1: t1 already forced-retired by compute(0)'s A-dependency waits
    // (FIFO: t1 older than A0); vmcnt(12) is cheap insurance.
    afetch(1, a);
    asm volatile("s_waitcnt vmcnt(12)" ::: "memory");
    __builtin_amdgcn_s_barrier();
    __builtin_amdgcn_sched_barrier(0);
    stage(3, 0);   // buf0: last read in compute(0); all waves past this barrier
    compute(1, a);

    // kt=2
    afetch(2, a);
    asm volatile("s_waitcnt vmcnt(12)" ::: "memory");
    __builtin_amdgcn_s_barrier();
    __builtin_amdgcn_sched_barrier(0);
    compute(2, a);

    // kt=3: tile 3 lives in buf0 (R8 bug: read bst[3] = OOB)
    afetch(3, a);
    asm volatile("s_waitcnt vmcnt(8)" ::: "memory");
    __builtin_amdgcn_s_barrier();
    __builtin_amdgcn_sched_barrier(0);
    compute(0, a);

    // ---- epilogue: D (32x32): col = lane&31, row = (r&3) + 8*(r>>2) + 4*lh
    float* outb = out + (size_t)b * 256 * 4096 + hw0;
#pragma unroll
    for (int mtl = 0; mtl < 2; mtl++)
#pragma unroll
        for (int ntl = 0; ntl < 2; ntl++)
#pragma unroll
            for (int r = 0; r < 16; r++) {
                const int row = o0 + mtl * 32 + (r & 3) + 8 * (r >> 2) + 4 * lh;
                outb[(size_t)row * 4096 + ntl * 32 + l31] = acc[mtl][ntl][r] + b1[row];
            }
}

extern "C" void kernel_launch(void* const* d_in, const int* in_sizes, int n_in,
                              void* d_out, int out_size, void* d_ws, size_t ws_size,
                              hipStream_t stream) {
    const float* x = (const float*)d_in[0];
    const float* context = (const float*)d_in[1];
    const float* w1 = (const float*)d_in[2];
    const float* b1 = (const float*)d_in[3];
    float* out = (float*)d_out;

    float* scale = (float*)d_ws;                                   // 16 KB
    unsigned short* w2f = (unsigned short*)((char*)d_ws + 16384);  // 2 MB

    scale_kernel<<<4096, 256, 0, stream>>>(context, scale);
    w2f_kernel<<<512, 256, 0, stream>>>(w1, scale, w2f);
    gemm_kernel<<<1024, 256, 0, stream>>>(x, w2f, b1, out);
}

// Round 12
// 42.552 us; speedup vs baseline: 1.0192x; 1.0192x over previous
//
#include <hip/hip_runtime.h>
#include <hip/hip_bf16.h>

// Problem: B=16, C=256, H=64, W=64, OUT=256
//   scale[b,c] = mean(context[b,c,:,:])
//   out[b,o,hw] = sum_c w1[o,c]*scale[b,c]*x[b,c,hw] + b1[o]
// R12: R10's geometry (BN=128, 512 blocks = exact 2/CU zero-tail, XCD swizzle,
//      halved A-traffic) on R7's PROVEN __syncthreads double-buffer pipeline
//      (counted-vmcnt line abandoned: R10/R11 failed unexplainably and R9
//      proved it gains ~0 at this size). One safe overlap fix: afetch(kt)
//      issued BEFORE stage(kt+1), so the compiler's auto-wait for A-fragments
//      (FIFO: A older) leaves staging loads in flight under compute.

typedef __attribute__((ext_vector_type(8))) short short8;
typedef __attribute__((ext_vector_type(16))) float f32x16;
typedef __attribute__((ext_vector_type(4))) unsigned int u32x4;

static __device__ __forceinline__ unsigned int bfbits(float f) {
    unsigned int u = __float_as_uint(f);
    return u + 0x7FFFu + ((u >> 16) & 1u);  // bf16 (RTNE) in bits 16..31
}

static __device__ __forceinline__ unsigned int pkbf(float lo, float hi) {
#if __has_builtin(__builtin_amdgcn_perm)
    return __builtin_amdgcn_perm(bfbits(hi), bfbits(lo), 0x07060302u);
#else
    return (bfbits(lo) >> 16) | (bfbits(hi) & 0xffff0000u);
#endif
}

// async global->LDS, 16B per lane (linear LDS dest: wave base + lane*16)
static __device__ __forceinline__ void gload16(const void* g, void* l) {
    __builtin_amdgcn_global_load_lds(
        (const __attribute__((address_space(1))) unsigned int*)g,
        (__attribute__((address_space(3))) unsigned int*)l, 16, 0, 0);
}

// ---------------- Kernel 1: scale[b*256+c] = mean over 4096 elems ----------
__global__ __launch_bounds__(256) void scale_kernel(const float* __restrict__ ctx,
                                                    float* __restrict__ scale) {
    const int bc = blockIdx.x;              // 0..4095
    const float4* p = (const float4*)(ctx + (size_t)bc * 4096);
    const int t = threadIdx.x;
    float s = 0.f;
#pragma unroll
    for (int k = 0; k < 4; k++) {
        float4 v = p[t + k * 256];
        s += v.x + v.y + v.z + v.w;
    }
#pragma unroll
    for (int off = 32; off > 0; off >>= 1) s += __shfl_down(s, off);
    __shared__ float ws[4];
    if ((t & 63) == 0) ws[t >> 6] = s;
    __syncthreads();
    if (t == 0) scale[bc] = (ws[0] + ws[1] + ws[2] + ws[3]) * (1.0f / 4096.0f);
}

// ---------------- Kernel 2: w2f = scale-folded w1, 32x32x16-fragment layout -
// w2f (ushort): [((b*16+ks)*8 + mt)*64 + lane]*8 + e
//   = bf16( w1[mt*32+(lane&31)][ks*16+(lane>>5)*8+e] * scale[b][same c] )
__global__ __launch_bounds__(256) void w2f_kernel(const float* __restrict__ w1,
                                                  const float* __restrict__ scale,
                                                  unsigned short* __restrict__ w2f) {
    const int gt = blockIdx.x * 256 + threadIdx.x;  // 0..131071
    const int l = gt & 63;
    const int mt = (gt >> 6) & 7;
    const int ks = (gt >> 9) & 15;
    const int b = gt >> 13;
    const int row = mt * 32 + (l & 31);
    const int c0 = ks * 16 + (l >> 5) * 8;

    const float* wr = w1 + row * 256 + c0;
    const float* sc = scale + b * 256 + c0;
    float4 wv0 = *(const float4*)(wr);
    float4 wv1 = *(const float4*)(wr + 4);
    float4 sv0 = *(const float4*)(sc);
    float4 sv1 = *(const float4*)(sc + 4);

    u32x4 pv;
    pv[0] = pkbf(wv0.x * sv0.x, wv0.y * sv0.y);
    pv[1] = pkbf(wv0.z * sv0.z, wv0.w * sv0.w);
    pv[2] = pkbf(wv1.x * sv1.x, wv1.y * sv1.y);
    pv[3] = pkbf(wv1.z * sv1.z, wv1.w * sv1.w);
    *(u32x4*)(w2f + (size_t)gt * 8) = pv;   // coalesced 16B store
}

// ---------------- Kernel 3: per-batch GEMM out = A(w2f) * bf16(x) + b1 ------
// 512 blocks, XCD-swizzled: work = (bid&7)*64 + bid>>3 (bijective); b = work>>5,
// col tile (work&31)*128. 4 waves; wave w = rows [64w,+64) x 128 cols
// (2 mtl x 4 ntl MFMA-32x32 tiles). B staged f32 [64k][128c] (32KB), 2-buffered,
// __syncthreads per kt (R7's proven scheme).
__global__ __launch_bounds__(256, 2) void gemm_kernel(const float* __restrict__ x,
                                                      const unsigned short* __restrict__ w2f,
                                                      const float* __restrict__ b1,
                                                      float* __restrict__ out) {
    __shared__ float bst[2][8192];     // 2 x (64k x 128c f32) = 64 KiB

    const int bid = blockIdx.x;        // 512
    const int work = (bid & 7) * 64 + (bid >> 3);   // XCD-contiguous
    const int b = work >> 5;           // batch (2 per XCD)
    const int hw0 = (work & 31) * 128; // column tile base
    const int tid = threadIdx.x;
    const int w = tid >> 6;
    const int lane = tid & 63;
    const int l31 = lane & 31;
    const int lh = lane >> 5;          // 0/1
    const int o0 = w * 64;

    const unsigned short* Af = w2f + (size_t)b * 65536;   // [16ks][8mt][64l][8]
    const float* Xb = x + (size_t)b * (256 * 4096) + hw0;

    f32x16 acc[2][4];
#pragma unroll
    for (int mtl = 0; mtl < 2; mtl++)
#pragma unroll
        for (int ntl = 0; ntl < 4; ntl++) acc[mtl][ntl] = (f32x16)(0.f);

    const int bbase = lh * 1024 + l31;  // dword idx; + sub*2048 + e*128 + ntl*32

    auto stage = [&](int kt, int buf) {
#pragma unroll
        for (int i = 0; i < 8; i++) {
            const int idx = i * 256 + tid;          // granule 0..2047
            gload16(Xb + (size_t)(kt * 64 + (idx >> 5)) * 4096 + (idx & 31) * 4,
                    &bst[buf][idx * 4]);
        }
    };
    auto afetch = [&](int kt, short8 a[4][2]) {
#pragma unroll
        for (int sub = 0; sub < 4; sub++)
#pragma unroll
            for (int mtl = 0; mtl < 2; mtl++)
                a[sub][mtl] = *(const short8*)(
                    Af + (((size_t)(kt * 4 + sub) * 8 + (w * 2 + mtl)) * 64 + lane) * 8);
    };
    auto compute = [&](int buf, short8 a[4][2]) {
        const float* bb = bst[buf];
#pragma unroll
        for (int sub = 0; sub < 4; sub++) {
#pragma unroll
            for (int ntl = 0; ntl < 4; ntl++) {
                float bf32[8];
#pragma unroll
                for (int e = 0; e < 8; e++)
                    bf32[e] = bb[bbase + sub * 2048 + e * 128 + ntl * 32];
                u32x4 pv;
#pragma unroll
                for (int j = 0; j < 4; j++) pv[j] = pkbf(bf32[2 * j], bf32[2 * j + 1]);
                short8 bfr = __builtin_bit_cast(short8, pv);
#pragma unroll
                for (int mtl = 0; mtl < 2; mtl++)
                    acc[mtl][ntl] = __builtin_amdgcn_mfma_f32_32x32x16_bf16(
                        a[sub][mtl], bfr, acc[mtl][ntl], 0, 0, 0);
            }
        }
    };

    // prologue: stage tile 0, full drain at barrier (syncthreads = vmcnt0+lgkm0)
    stage(0, 0);
    __syncthreads();

    short8 a[4][2];
#pragma unroll
    for (int kt = 0; kt < 4; kt++) {
        // A first (older in VMEM FIFO): the auto-wait before the first MFMA
        // retires only A, leaving the 8 staging loads below in flight.
        afetch(kt, a);
        if (kt < 3) stage(kt + 1, (kt + 1) & 1);
        compute(kt & 1, a);
        __syncthreads();   // drains staging (vmcnt0) + all waves done reading
    }

    // ---- epilogue: D (32x32): col = lane&31, row = (r&3) + 8*(r>>2) + 4*lh
    float* outb = out + (size_t)b * 256 * 4096 + hw0;
#pragma unroll
    for (int mtl = 0; mtl < 2; mtl++)
#pragma unroll
        for (int ntl = 0; ntl < 4; ntl++)
#pragma unroll
            for (int r = 0; r < 16; r++) {
                const int row = o0 + mtl * 32 + (r & 3) + 8 * (r >> 2) + 4 * lh;
                outb[(size_t)row * 4096 + ntl * 32 + l31] = acc[mtl][ntl][r] + b1[row];
            }
}

extern "C" void kernel_launch(void* const* d_in, const int* in_sizes, int n_in,
                              void* d_out, int out_size, void* d_ws, size_t ws_size,
                              hipStream_t stream) {
    const float* x = (const float*)d_in[0];
    const float* context = (const float*)d_in[1];
    const float* w1 = (const float*)d_in[2];
    const float* b1 = (const float*)d_in[3];
    float* out = (float*)d_out;

    float* scale = (float*)d_ws;                                   // 16 KB
    unsigned short* w2f = (unsigned short*)((char*)d_ws + 16384);  // 2 MB

    scale_kernel<<<4096, 256, 0, stream>>>(context, scale);
    w2f_kernel<<<512, 256, 0, stream>>>(w1, scale, w2f);
    gemm_kernel<<<512, 256, 0, stream>>>(x, w2f, b1, out);
}